// Round 9
// baseline (3236.937 us; speedup 1.0000x reference)
//
#include <hip/hip_runtime.h>
#include <stdint.h>
#include <math.h>

// ---------------- problem constants ----------------
#define BB 32
#define TT 1024
#define CIN 128
#define FF 256
#define KW 5
#define HH 512
#define TP 510          // conv output length (VALID, stride 2)
#define TLAST 509
#define KC 640          // conv GEMM K  (5*128)
#define GWG 256         // scan workgroups: 8 groups x 32 wgs

// ---------------- workspace layout (bytes) ----------------
// parts words are tagged (tag<<32|payload): no init needed (0xAA poison never
// matches tags 1..510). h words untagged u32, certified by parts tags.
#define HPK_OFF     0ull          // h u32: [8 grp][par2][4b][512u] = 131072
#define PRT_OFF     131072ull     // parts u64: [8 grp][par2][4b][32wg] = 16384
#define XP_OFF      278528ull                         // fp32 [8grp][512 t'][32 slot][4q][16jj][4b] = 134217728
#define XH_OFF      (XP_OFF + 134217728ull)           // x hi bf16 [4194304]
#define XL_OFF      (XH_OFF + 8388608ull)
#define XSH_OFF     (XL_OFF + 8388608ull)             // xs hi bf16 [16384][256]
#define XSL_OFF     (XSH_OFF + 8388608ull)
#define WCH_OFF     (XSL_OFF + 8388608ull)            // conv W [256][640] hi
#define WCL_OFF     (WCH_OFF + 327680ull)
#define WIHH_OFF    (WCL_OFF + 327680ull)             // w_ih [2048][256] hi
#define WIHL_OFF    (WIHH_OFF + 1048576ull)
#define WS_NEED     (WIHL_OFF + 1048576ull)           // ~163.5 MiB

typedef unsigned short u16;
typedef unsigned long long u64;
typedef __attribute__((ext_vector_type(8))) short short8;
typedef __attribute__((ext_vector_type(4))) float f32x4;
typedef __attribute__((ext_vector_type(4))) unsigned int u32x4;

__device__ __forceinline__ u16 f2bf(float f) {
  uint32_t u = __float_as_uint(f);
  u += 0x7fffu + ((u >> 16) & 1u);      // RNE
  return (u16)(u >> 16);
}
__device__ __forceinline__ float bf2f(u16 s) { return __uint_as_float(((uint32_t)s) << 16); }
__device__ __forceinline__ void splitf(float v, u16& h, u16& l) {
  h = f2bf(v);
  l = f2bf(v - bf2f(h));
}
__device__ __forceinline__ float sigm(float x) { return 1.f / (1.f + expf(-x)); }

// ---------------- prep: split x / conv_w(transposed) / w_ih into bf16 hi+lo ----------------
__global__ void prep_kernel(const float* __restrict__ x, const float* __restrict__ conv_w,
                            const float* __restrict__ w_ih,
                            u16* __restrict__ xh, u16* __restrict__ xl,
                            u16* __restrict__ wch, u16* __restrict__ wcl,
                            u16* __restrict__ wihh, u16* __restrict__ wihl) {
  int i = blockIdx.x * 256 + threadIdx.x;
  if (i < 4194304) {
    u16 h, l; splitf(x[i], h, l); xh[i] = h; xl[i] = l;
  } else if (i < 4194304 + 163840) {
    int j = i - 4194304;
    int f = j / 640, kk = j % 640;
    int c = kk & 127, k = kk >> 7;                 // kk = k*128 + c
    u16 h, l; splitf(conv_w[f * 640 + c * 5 + k], h, l);
    wch[f * 640 + kk] = h; wcl[f * 640 + kk] = l;
  } else if (i < 4194304 + 163840 + 524288) {
    int j = i - (4194304 + 163840);
    u16 h, l; splitf(w_ih[j], h, l); wihh[j] = h; wihl[j] = l;
  }
}

// ---------------- split-bf16 GEMM, 128x128 tile, BK=32, frag-order LDS ----------------
// MODE 0: conv  (K=640, B = windowed x, epilogue relu+BN -> xs hi/lo bf16 at [n][f])
// MODE 1: proj  (K=256, B = xs rows,    epilogue +bias   -> xp fp32, scan-coalesced layout)
template <int MODE>
__global__ __launch_bounds__(256, 1) void gemm_kernel(
    const u16* __restrict__ Ah, const u16* __restrict__ Al,
    const u16* __restrict__ Bh, const u16* __restrict__ Bl,
    const float* __restrict__ e0, const float* __restrict__ e1,
    const float* __restrict__ e2, const float* __restrict__ e3, const float* __restrict__ e4,
    u16* __restrict__ outh, u16* __restrict__ outl, float* __restrict__ outf) {
  const int KDIM = (MODE == 0) ? KC : 256;
  const int MT   = (MODE == 0) ? 2 : 16;
  int bx = blockIdx.x;
  int m0 = (bx % MT) * 128;
  int n0 = (bx / MT) * 128;
  __shared__ __attribute__((aligned(16))) u16 lds[4][4096];
  int t = threadIdx.x;
  int wave = t >> 6, lane = t & 63;
  int wm = wave & 1, wn = wave >> 1;

  f32x4 acc[4][4];
#pragma unroll
  for (int i = 0; i < 4; i++)
#pragma unroll
    for (int j = 0; j < 4; j++) acc[i][j] = (f32x4){0.f, 0.f, 0.f, 0.f};

  for (int k0 = 0; k0 < KDIM; k0 += 32) {
    __syncthreads();
#pragma unroll
    for (int half = 0; half < 2; half++) {
      int e = half * 256 + t;
      int l = e & 63, tile = e >> 6;
      int kk = k0 + ((l >> 4) * 8);
      {
        int row = m0 + tile * 16 + (l & 15);
        const u16* sh = Ah + (long)row * KDIM + kk;
        const u16* sl = Al + (long)row * KDIM + kk;
        *(short8*)&lds[0][e * 8] = *(const short8*)sh;
        *(short8*)&lds[1][e * 8] = *(const short8*)sl;
      }
      {
        int n = n0 + tile * 16 + (l & 15);
        long base;
        if (MODE == 0) {
          int tp = n >> 5; if (tp > TLAST) tp = TLAST;
          base = (long)(n & 31) * 131072 + (long)tp * 256;
        } else {
          base = (long)n * 256;
        }
        *(short8*)&lds[2][e * 8] = *(const short8*)(Bh + base + kk);
        *(short8*)&lds[3][e * 8] = *(const short8*)(Bl + base + kk);
      }
    }
    __syncthreads();
    short8 af[4][2], bf[4][2];
#pragma unroll
    for (int i = 0; i < 4; i++) {
      af[i][0] = *(const short8*)&lds[0][((wm * 4 + i) * 64 + lane) * 8];
      af[i][1] = *(const short8*)&lds[1][((wm * 4 + i) * 64 + lane) * 8];
      bf[i][0] = *(const short8*)&lds[2][((wn * 4 + i) * 64 + lane) * 8];
      bf[i][1] = *(const short8*)&lds[3][((wn * 4 + i) * 64 + lane) * 8];
    }
#pragma unroll
    for (int am = 0; am < 4; am++)
#pragma unroll
      for (int an = 0; an < 4; an++) {
        acc[am][an] = __builtin_amdgcn_mfma_f32_16x16x32_bf16(af[am][0], bf[an][0], acc[am][an], 0, 0, 0);
        acc[am][an] = __builtin_amdgcn_mfma_f32_16x16x32_bf16(af[am][0], bf[an][1], acc[am][an], 0, 0, 0);
        acc[am][an] = __builtin_amdgcn_mfma_f32_16x16x32_bf16(af[am][1], bf[an][0], acc[am][an], 0, 0, 0);
      }
  }
#pragma unroll
  for (int am = 0; am < 4; am++)
#pragma unroll
    for (int an = 0; an < 4; an++) {
      int n = n0 + (wn * 4 + an) * 16 + (lane & 15);
#pragma unroll
      for (int r = 0; r < 4; r++) {
        int m = m0 + (wm * 4 + am) * 16 + (lane >> 4) * 4 + r;
        float v = acc[am][an][r];
        if (MODE == 0) {
          float inv = e1[m] / sqrtf(e4[m] + 1e-5f);
          float sh  = e2[m] - e3[m] * inv;
          v = fmaxf(v + e0[m], 0.f) * inv + sh;
          u16 h, l; splitf(v, h, l);
          outh[(long)n * 256 + m] = h;
          outl[(long)n * 256 + m] = l;
        } else {
          v += e0[m] + e1[m];
          int tp = n >> 5, b = n & 31;
          int grp = b >> 2, bb = b & 3;
          int q = m >> 9, unit = m & 511;
          int sl = unit >> 4, jjj = unit & 15;
          outf[(((long)grp * 512 + tp) * 32 + sl) * 256 + q * 64 + jjj * 4 + bb] = v;
        }
      }
    }
}

// ---------------- persistent skip-LSTM scan (certify-via-parts, per-wave staging) ----------------
// 8 groups x 32 wgs; group = blockIdx&7 (XCD-locality heuristic), slot = blockIdx>>3.
// Group owns batches [4g,4g+4), all 512 units; wg owns 16 units, W_hh pre-split in regs.
// NEW vs r7: wave w stages ONLY its K-quarter [128w,128w+128) (8 producers) into its
// own LDS region -> no staging barrier, per-wave fan-in 8, waves proceed to MFMA
// independently. gpart double-buffered by parity; ONE barrier per step. Producer
// (wave0 epilogue): h stores (untagged u32, coalesced) -> s_waitcnt vmcnt(0) ->
// 4 tagged parts u64 (the certs). Consumer lane polls its single producer's cert;
// tag==s certifies that producer's h at the LLC -> retry-free 32B bulk load.
// Overwrite safety: the wg's 4 waves collectively observe all 32 tag-s certs before
// the step-s barrier => every wg finished step s-1 => parity buffers holding tag
// s-1 data are dead when overwritten at end of step s. (Same chain as r7.)
__global__ __launch_bounds__(256, 1) void scan_kernel(
    const float* __restrict__ xpg,    // [8][512][32][256]
    const float* __restrict__ w_hh,   // [2048][512]
    const float* __restrict__ w_uh,   // [512]
    const float* __restrict__ b_uh_p, // [1]
    uint32_t* __restrict__ hpk,       // [8][2][4][512] u32 (hi16|lo16)
    u64* __restrict__ prt,            // [8][2][4][32] tagged
    float* __restrict__ outp)         // [32][512]
{
  __shared__ __attribute__((aligned(16))) u16 sh_hi[4 * 528];  // [4b][512+16 pad]
  __shared__ __attribute__((aligned(16))) u16 sh_lo[4 * 528];
  __shared__ float gpart[2][4][4][16][4];  // [par][wave][gate][row][batch]
  __shared__ float sparts[4][32];
  __shared__ float u_l[4], ubin_l[4];
  __shared__ float wuh_l[16];
  int group = blockIdx.x & 7, slot = blockIdx.x >> 3;
  int t = threadIdx.x;
  int wave = t >> 6, lane = t & 63;
  int um = lane & 15, kq = lane >> 4;
  int nbc = um & 3;

  if (t < 16) wuh_l[t] = w_uh[slot * 16 + t];
  if (t < 4)  { u_l[t] = 1.0f; ubin_l[t] = 1.0f; }

  // ---- preload W_hh fragments: wave w covers K[128w..128w+128) for gates 0..3
  short8 wfh[4][4], wfl[4][4];
#pragma unroll
  for (int q = 0; q < 4; q++) {
    long row = (long)(q * 512 + slot * 16 + um) * 512;
#pragma unroll
    for (int k4 = 0; k4 < 4; k4++) {
      union { short8 v; u16 u[8]; } Uh, Ul;
      long col0 = wave * 128 + k4 * 32 + kq * 8;
#pragma unroll
      for (int i = 0; i < 8; i++) splitf(w_hh[row + col0 + i], Uh.u[i], Ul.u[i]);
      wfh[q][k4] = Uh.v; wfl[q][k4] = Ul.v;
    }
  }
  float bu = b_uh_p[0];

  int jj = t & 15, bbt = t >> 4;        // wave0 cell mapping (contiguous h stores)
  float c_reg = 0.f, h_reg = 0.f;

  uint32_t* hgrp = hpk + (long)group * 4096;   // [par][4b][512] u32
  u64*      pgrp = prt + (long)group * 256;    // [par][4b][32]

  // staging lane mapping (per wave): batch sb, 8 units at quarter offset su
  int sb = lane >> 4;
  int su = (lane & 15) * 8;
  int unit0 = wave * 128 + su;
  int pslot = wave * 8 + ((lane & 15) >> 1);   // the ONE producer of this lane's share

  __syncthreads();

  for (int s = 0; s < TP; s++) {
    int par = s & 1, np = par ^ 1;
    // xq for CURRENT step (wave0 cells), issued before any polls
    f32x4 xq;
    if (wave == 0) {
      const float* xb = xpg + (((long)group * 512 + s) * 32 + slot) * 256;
      float x0 = xb[0 * 64 + jj * 4 + bbt];
      float x1 = xb[1 * 64 + jj * 4 + bbt];
      float x2 = xb[2 * 64 + jj * 4 + bbt];
      float x3 = xb[3 * 64 + jj * 4 + bbt];
      xq = (f32x4){x0, x1, x2, x3};
    }
    // ---- per-wave staging of OWN K-quarter (no barrier needed before MFMA)
    if (s == 0) {
      *(u32x4*)&sh_hi[sb * 528 + unit0] = (u32x4){0u, 0u, 0u, 0u};
      *(u32x4*)&sh_lo[sb * 528 + unit0] = (u32x4){0u, 0u, 0u, 0u};
    } else {
      const u64* pw = pgrp + (long)par * 128 + sb * 32 + pslot;
      u64 w;
      do { w = __hip_atomic_load(pw, __ATOMIC_RELAXED, __HIP_MEMORY_SCOPE_AGENT); }
      while ((uint32_t)(w >> 32) != (uint32_t)s);
      // certified: that producer's h is LLC-visible; bulk-load retry-free
      const u64* hp = (const u64*)(hgrp + (long)par * 2048 + sb * 512 + unit0);
      u64 v0 = __hip_atomic_load(hp,     __ATOMIC_RELAXED, __HIP_MEMORY_SCOPE_AGENT);
      u64 v1 = __hip_atomic_load(hp + 1, __ATOMIC_RELAXED, __HIP_MEMORY_SCOPE_AGENT);
      u64 v2 = __hip_atomic_load(hp + 2, __ATOMIC_RELAXED, __HIP_MEMORY_SCOPE_AGENT);
      u64 v3 = __hip_atomic_load(hp + 3, __ATOMIC_RELAXED, __HIP_MEMORY_SCOPE_AGENT);
      uint32_t p[8] = {(uint32_t)v0, (uint32_t)(v0 >> 32), (uint32_t)v1, (uint32_t)(v1 >> 32),
                       (uint32_t)v2, (uint32_t)(v2 >> 32), (uint32_t)v3, (uint32_t)(v3 >> 32)};
      u32x4 hv, lv;
#pragma unroll
      for (int r = 0; r < 4; r++) {
        hv[r] = __builtin_amdgcn_perm(p[2 * r + 1], p[2 * r], 0x07060302u);
        lv[r] = __builtin_amdgcn_perm(p[2 * r + 1], p[2 * r], 0x05040100u);
      }
      *(u32x4*)&sh_hi[sb * 528 + unit0] = hv;
      *(u32x4*)&sh_lo[sb * 528 + unit0] = lv;
    }
    asm volatile("" ::: "memory");   // keep LDS writes before the reads below
    // ---- MFMA on own quarter (intra-wave LDS ordering; no barrier)
    f32x4 A0[4], A1[4], A2[4];
#pragma unroll
    for (int q = 0; q < 4; q++) {
      A0[q] = (f32x4){0.f, 0.f, 0.f, 0.f}; A1[q] = A0[q]; A2[q] = A0[q];
    }
#pragma unroll
    for (int k4 = 0; k4 < 4; k4++) {
      int ko = (wave * 4 + k4) * 32 + kq * 8;
      short8 bh = *(const short8*)&sh_hi[nbc * 528 + ko];
      short8 bl = *(const short8*)&sh_lo[nbc * 528 + ko];
#pragma unroll
      for (int q = 0; q < 4; q++) {
        A0[q] = __builtin_amdgcn_mfma_f32_16x16x32_bf16(wfh[q][k4], bh, A0[q], 0, 0, 0);
        A1[q] = __builtin_amdgcn_mfma_f32_16x16x32_bf16(wfh[q][k4], bl, A1[q], 0, 0, 0);
        A2[q] = __builtin_amdgcn_mfma_f32_16x16x32_bf16(wfl[q][k4], bh, A2[q], 0, 0, 0);
      }
    }
    if (um < 4) {
#pragma unroll
      for (int q = 0; q < 4; q++)
#pragma unroll
        for (int r = 0; r < 4; r++)
          gpart[par][wave][q][kq * 4 + r][um] = (A0[q][r] + A1[q][r]) + A2[q][r];
    }
    // ---- wave0: bulk parts load for u-update (certs tag-s mostly committed by now;
    //      retry loop is the safety net). lanes cover idx = lane and lane+64.
    if (wave == 0 && s > 0) {
#pragma unroll
      for (int h2 = 0; h2 < 2; h2++) {
        int idx = lane + h2 * 64;
        const u64* pw2 = pgrp + (long)par * 128 + idx;
        u64 w2;
        do { w2 = __hip_atomic_load(pw2, __ATOMIC_RELAXED, __HIP_MEMORY_SCOPE_AGENT); }
        while ((uint32_t)(w2 >> 32) != (uint32_t)s);
        sparts[idx >> 5][idx & 31] = __uint_as_float((uint32_t)w2);
      }
    }
    __syncthreads();   // ONE barrier/step: gparts complete; waves may run 1 step ahead (parity dbuf)
    // ---- epilogue (wave 0 only); waves 1-3 loop ahead into next staging
    if (wave == 0) {
      if (s > 0 && lane < 4) {
        float a = 0.f;
#pragma unroll
        for (int i = 0; i < 32; i++) a += sparts[lane][i];
        float du = sigm(a + bu);
        float up = u_l[lane], ubp = ubin_l[lane];
        float un = (ubp > 0.5f) ? du : (up + fminf(du, 1.f - up));
        u_l[lane] = un; ubin_l[lane] = rintf(un);
      }
      float g[4];
#pragma unroll
      for (int q = 0; q < 4; q++) {
        float a = xq[q];
#pragma unroll
        for (int w = 0; w < 4; w++) a += gpart[par][w][q][jj][bbt];
        g[q] = a;
      }
      float ig = sigm(g[0]), fg = sigm(g[1]), og = sigm(g[3]);
      float gt = tanhf(g[2]);
      float ct = fg * c_reg + ig * gt;
      float ht = og * tanhf(ct);
      bool upd = ubin_l[bbt] > 0.5f;
      float cn = upd ? ct : c_reg;
      float hn = upd ? ht : h_reg;
      c_reg = cn; h_reg = hn;
      u16 hhi, hlo; splitf(hn, hhi, hlo);
      uint32_t pk = ((uint32_t)hhi << 16) | (uint32_t)hlo;
      // untagged h store: lanes contiguous in jj -> 4 chunks of 64B
      __hip_atomic_store(hgrp + (long)np * 2048 + bbt * 512 + slot * 16 + jj, pk,
                         __ATOMIC_RELAXED, __HIP_MEMORY_SCOPE_AGENT);
      float pr = cn * wuh_l[jj];
      pr += __shfl_xor(pr, 1); pr += __shfl_xor(pr, 2);
      pr += __shfl_xor(pr, 4); pr += __shfl_xor(pr, 8);
      if (s == TLAST) outp[(long)(group * 4 + bbt) * 512 + slot * 16 + jj] = hn;
      // h stores ack'd at the LLC BEFORE the certifying parts store
      asm volatile("s_waitcnt vmcnt(0)" ::: "memory");
      if ((lane & 15) == 0) {
        u64 pw = ((u64)(uint32_t)(s + 1) << 32) | (u64)__float_as_uint(pr);
        __hip_atomic_store(pgrp + (long)np * 128 + bbt * 32 + slot, pw,
                           __ATOMIC_RELAXED, __HIP_MEMORY_SCOPE_AGENT);
      }
    }
    // no trailing barrier: waves 1-3 start next staging (global polls + their own
    // LDS quarter + gpart[np]) — all disjoint from wave0's reads of gpart[par].
  }
}

// ---------------- launcher ----------------
extern "C" void kernel_launch(void* const* d_in, const int* in_sizes, int n_in,
                              void* d_out, int out_size, void* d_ws, size_t ws_size,
                              hipStream_t stream) {
  const float* x      = (const float*)d_in[0];
  const float* conv_w = (const float*)d_in[1];
  const float* conv_b = (const float*)d_in[2];
  const float* gamma  = (const float*)d_in[3];
  const float* beta   = (const float*)d_in[4];
  const float* mean   = (const float*)d_in[5];
  const float* var    = (const float*)d_in[6];
  const float* w_ih   = (const float*)d_in[7];
  const float* w_hh   = (const float*)d_in[8];
  const float* b_ih   = (const float*)d_in[9];
  const float* b_hh   = (const float*)d_in[10];
  const float* w_uh   = (const float*)d_in[11];
  const float* b_uh   = (const float*)d_in[12];
  float* out = (float*)d_out;

  if (ws_size < WS_NEED) return;  // workspace too small: fail visibly via absmax

  char* w = (char*)d_ws;
  uint32_t* hpk = (uint32_t*)(w + HPK_OFF);
  u64*   prt   = (u64*)(w + PRT_OFF);
  float* xp    = (float*)(w + XP_OFF);
  u16*   xh    = (u16*)(w + XH_OFF);
  u16*   xl    = (u16*)(w + XL_OFF);
  u16*   xsh   = (u16*)(w + XSH_OFF);
  u16*   xsl   = (u16*)(w + XSL_OFF);
  u16*   wch   = (u16*)(w + WCH_OFF);
  u16*   wcl   = (u16*)(w + WCL_OFF);
  u16*   wihh  = (u16*)(w + WIHH_OFF);
  u16*   wihl  = (u16*)(w + WIHL_OFF);

  // no memset: parts tags self-validate (0xAA poison never matches 1..510);
  // h validity is certified by parts tags; h0/c0/u0 are zeros inside scan_kernel.

  prep_kernel<<<19072, 256, 0, stream>>>(x, conv_w, w_ih, xh, xl, wch, wcl, wihh, wihl);

  // conv GEMM: M=256(f) N=16384 K=640 -> xs (relu+BN, bf16 hi/lo, [n][f])
  gemm_kernel<0><<<2 * 128, 256, 0, stream>>>(wch, wcl, xh, xl,
                                              conv_b, gamma, beta, mean, var,
                                              xsh, xsl, nullptr);
  // proj GEMM: M=2048(g) N=16384 K=256 -> xp fp32 scan-coalesced (+ b_ih + b_hh)
  gemm_kernel<1><<<16 * 128, 256, 0, stream>>>(wihh, wihl, xsh, xsl,
                                               b_ih, b_hh, nullptr, nullptr, nullptr,
                                               nullptr, nullptr, xp);
  // persistent scan: 8 groups x 32 wgs, certify-via-parts + per-wave quarter staging
  scan_kernel<<<GWG, 256, 0, stream>>>(xp, w_hh, w_uh, b_uh, hpk, prt, out);
}

// Round 10
// 2252.238 us; speedup vs baseline: 1.4372x; 1.4372x over previous
//
#include <hip/hip_runtime.h>
#include <stdint.h>
#include <math.h>

// ---------------- problem constants ----------------
#define BB 32
#define TT 1024
#define CIN 128
#define FF 256
#define KW 5
#define HH 512
#define TP 510          // conv output length (VALID, stride 2)
#define TLAST 509
#define KC 640          // conv GEMM K  (5*128)
#define GWG 256         // scan workgroups: 8 groups x 32 wgs

// ---------------- workspace layout (bytes) ----------------
// parts words are tagged (tag<<32|payload): no init needed (0xAA poison never
// matches tags 1..510). h words untagged u32, certified by parts tags.
#define HPK_OFF     0ull          // h u32: [8 grp][par2][4b][512u] = 131072
#define PRT_OFF     131072ull     // parts u64: [8 grp][par2][4b][32wg] = 16384
#define XP_OFF      278528ull                         // fp32 [8grp][512 t'][32 slot][4q][16jj][4b] = 134217728
#define XH_OFF      (XP_OFF + 134217728ull)           // x hi bf16 [4194304]
#define XL_OFF      (XH_OFF + 8388608ull)
#define XSH_OFF     (XL_OFF + 8388608ull)             // xs hi bf16 [16384][256]
#define XSL_OFF     (XSH_OFF + 8388608ull)
#define WCH_OFF     (XSL_OFF + 8388608ull)            // conv W [256][640] hi
#define WCL_OFF     (WCH_OFF + 327680ull)
#define WIHH_OFF    (WCL_OFF + 327680ull)             // w_ih [2048][256] hi
#define WIHL_OFF    (WIHH_OFF + 1048576ull)
#define WS_NEED     (WIHL_OFF + 1048576ull)           // ~163.5 MiB

typedef unsigned short u16;
typedef unsigned long long u64;
typedef __attribute__((ext_vector_type(8))) short short8;
typedef __attribute__((ext_vector_type(4))) float f32x4;
typedef __attribute__((ext_vector_type(4))) unsigned int u32x4;

__device__ __forceinline__ u16 f2bf(float f) {
  uint32_t u = __float_as_uint(f);
  u += 0x7fffu + ((u >> 16) & 1u);      // RNE
  return (u16)(u >> 16);
}
__device__ __forceinline__ float bf2f(u16 s) { return __uint_as_float(((uint32_t)s) << 16); }
__device__ __forceinline__ void splitf(float v, u16& h, u16& l) {
  h = f2bf(v);
  l = f2bf(v - bf2f(h));
}
// fast transcendentals (v_exp_f32 path, ~1 ulp): keeps the scan epilogue's
// critical path free of branchy libm calls. Gate perturbation ~1e-6 << margin.
__device__ __forceinline__ float sigm(float x) {
  return __fdividef(1.f, 1.f + __expf(-x));
}
__device__ __forceinline__ float tanh_fast(float x) {
  float xc = fminf(x, 20.f);             // avoid inf/inf for large +x (tanh==1 there)
  float e = __expf(2.f * xc);
  return (e - 1.f) * __fdividef(1.f, e + 1.f);
}

// ---------------- prep: split x / conv_w(transposed) / w_ih into bf16 hi+lo ----------------
__global__ void prep_kernel(const float* __restrict__ x, const float* __restrict__ conv_w,
                            const float* __restrict__ w_ih,
                            u16* __restrict__ xh, u16* __restrict__ xl,
                            u16* __restrict__ wch, u16* __restrict__ wcl,
                            u16* __restrict__ wihh, u16* __restrict__ wihl) {
  int i = blockIdx.x * 256 + threadIdx.x;
  if (i < 4194304) {
    u16 h, l; splitf(x[i], h, l); xh[i] = h; xl[i] = l;
  } else if (i < 4194304 + 163840) {
    int j = i - 4194304;
    int f = j / 640, kk = j % 640;
    int c = kk & 127, k = kk >> 7;                 // kk = k*128 + c
    u16 h, l; splitf(conv_w[f * 640 + c * 5 + k], h, l);
    wch[f * 640 + kk] = h; wcl[f * 640 + kk] = l;
  } else if (i < 4194304 + 163840 + 524288) {
    int j = i - (4194304 + 163840);
    u16 h, l; splitf(w_ih[j], h, l); wihh[j] = h; wihl[j] = l;
  }
}

// ---------------- split-bf16 GEMM, 128x128 tile, BK=32, frag-order LDS ----------------
// MODE 0: conv  (K=640, B = windowed x, epilogue relu+BN -> xs hi/lo bf16 at [n][f])
// MODE 1: proj  (K=256, B = xs rows,    epilogue +bias   -> xp fp32, scan-coalesced layout)
template <int MODE>
__global__ __launch_bounds__(256, 1) void gemm_kernel(
    const u16* __restrict__ Ah, const u16* __restrict__ Al,
    const u16* __restrict__ Bh, const u16* __restrict__ Bl,
    const float* __restrict__ e0, const float* __restrict__ e1,
    const float* __restrict__ e2, const float* __restrict__ e3, const float* __restrict__ e4,
    u16* __restrict__ outh, u16* __restrict__ outl, float* __restrict__ outf) {
  const int KDIM = (MODE == 0) ? KC : 256;
  const int MT   = (MODE == 0) ? 2 : 16;
  int bx = blockIdx.x;
  int m0 = (bx % MT) * 128;
  int n0 = (bx / MT) * 128;
  __shared__ __attribute__((aligned(16))) u16 lds[4][4096];
  int t = threadIdx.x;
  int wave = t >> 6, lane = t & 63;
  int wm = wave & 1, wn = wave >> 1;

  f32x4 acc[4][4];
#pragma unroll
  for (int i = 0; i < 4; i++)
#pragma unroll
    for (int j = 0; j < 4; j++) acc[i][j] = (f32x4){0.f, 0.f, 0.f, 0.f};

  for (int k0 = 0; k0 < KDIM; k0 += 32) {
    __syncthreads();
#pragma unroll
    for (int half = 0; half < 2; half++) {
      int e = half * 256 + t;
      int l = e & 63, tile = e >> 6;
      int kk = k0 + ((l >> 4) * 8);
      {
        int row = m0 + tile * 16 + (l & 15);
        const u16* sh = Ah + (long)row * KDIM + kk;
        const u16* sl = Al + (long)row * KDIM + kk;
        *(short8*)&lds[0][e * 8] = *(const short8*)sh;
        *(short8*)&lds[1][e * 8] = *(const short8*)sl;
      }
      {
        int n = n0 + tile * 16 + (l & 15);
        long base;
        if (MODE == 0) {
          int tp = n >> 5; if (tp > TLAST) tp = TLAST;
          base = (long)(n & 31) * 131072 + (long)tp * 256;
        } else {
          base = (long)n * 256;
        }
        *(short8*)&lds[2][e * 8] = *(const short8*)(Bh + base + kk);
        *(short8*)&lds[3][e * 8] = *(const short8*)(Bl + base + kk);
      }
    }
    __syncthreads();
    short8 af[4][2], bf[4][2];
#pragma unroll
    for (int i = 0; i < 4; i++) {
      af[i][0] = *(const short8*)&lds[0][((wm * 4 + i) * 64 + lane) * 8];
      af[i][1] = *(const short8*)&lds[1][((wm * 4 + i) * 64 + lane) * 8];
      bf[i][0] = *(const short8*)&lds[2][((wn * 4 + i) * 64 + lane) * 8];
      bf[i][1] = *(const short8*)&lds[3][((wn * 4 + i) * 64 + lane) * 8];
    }
#pragma unroll
    for (int am = 0; am < 4; am++)
#pragma unroll
      for (int an = 0; an < 4; an++) {
        acc[am][an] = __builtin_amdgcn_mfma_f32_16x16x32_bf16(af[am][0], bf[an][0], acc[am][an], 0, 0, 0);
        acc[am][an] = __builtin_amdgcn_mfma_f32_16x16x32_bf16(af[am][0], bf[an][1], acc[am][an], 0, 0, 0);
        acc[am][an] = __builtin_amdgcn_mfma_f32_16x16x32_bf16(af[am][1], bf[an][0], acc[am][an], 0, 0, 0);
      }
  }
#pragma unroll
  for (int am = 0; am < 4; am++)
#pragma unroll
    for (int an = 0; an < 4; an++) {
      int n = n0 + (wn * 4 + an) * 16 + (lane & 15);
#pragma unroll
      for (int r = 0; r < 4; r++) {
        int m = m0 + (wm * 4 + am) * 16 + (lane >> 4) * 4 + r;
        float v = acc[am][an][r];
        if (MODE == 0) {
          float inv = e1[m] / sqrtf(e4[m] + 1e-5f);
          float sh  = e2[m] - e3[m] * inv;
          v = fmaxf(v + e0[m], 0.f) * inv + sh;
          u16 h, l; splitf(v, h, l);
          outh[(long)n * 256 + m] = h;
          outl[(long)n * 256 + m] = l;
        } else {
          v += e0[m] + e1[m];
          int tp = n >> 5, b = n & 31;
          int grp = b >> 2, bb = b & 3;
          int q = m >> 9, unit = m & 511;
          int sl = unit >> 4, jjj = unit & 15;
          outf[(((long)grp * 512 + tp) * 32 + sl) * 256 + q * 64 + jjj * 4 + bb] = v;
        }
      }
    }
}

// ---------------- persistent skip-LSTM scan (certify-via-parts, r7 skeleton) ----------------
// 8 groups x 32 wgs; group = blockIdx&7 (XCD-locality heuristic), slot = blockIdx>>3.
// Group owns batches [4g,4g+4), all 512 units; wg owns 16 units (64 gate rows),
// W_hh pre-split in registers. Producer (wave0 epilogue): store h (untagged u32,
// coalesced) -> __threadfence_block (s_waitcnt vmcnt(0): h ack'd at LLC, NO cache
// maintenance) -> store 4 TAGGED parts u64. Consumer staging thread: poll ONLY its
// single producer's parts word (doubles as the du-partial payload); tag==s
// certifies that producer's h at the LLC; then 8xu32 bulk load retry-free.
// Overwrite safety: reading tag-s parts from all producers implies all wgs passed
// step s-1 staging, so the parity buffer overwritten at end of step s is dead.
__global__ __launch_bounds__(256, 1) void scan_kernel(
    const float* __restrict__ xpg,    // [8][512][32][256]
    const float* __restrict__ w_hh,   // [2048][512]
    const float* __restrict__ w_uh,   // [512]
    const float* __restrict__ b_uh_p, // [1]
    uint32_t* __restrict__ hpk,       // [8][2][4][512] u32 (hi16|lo16)
    u64* __restrict__ prt,            // [8][2][4][32] tagged
    float* __restrict__ outp)         // [32][512]
{
  __shared__ __attribute__((aligned(16))) u16 sh_hi[4 * 528];
  __shared__ __attribute__((aligned(16))) u16 sh_lo[4 * 528];
  __shared__ float gpart[4][4][16][4];
  __shared__ float sparts[4][32];
  __shared__ float u_l[4], ubin_l[4];
  __shared__ float wuh_l[16];
  int group = blockIdx.x & 7, slot = blockIdx.x >> 3;
  int t = threadIdx.x;
  int wave = t >> 6, lane = t & 63;
  int um = lane & 15, kq = lane >> 4;
  int nbc = um & 3;

  if (t < 16) wuh_l[t] = w_uh[slot * 16 + t];
  if (t < 4)  { u_l[t] = 1.0f; ubin_l[t] = 1.0f; }

  // ---- preload W_hh fragments: wave w covers K[128w..128w+128) for gates 0..3
  short8 wfh[4][4], wfl[4][4];
#pragma unroll
  for (int q = 0; q < 4; q++) {
    long row = (long)(q * 512 + slot * 16 + um) * 512;
#pragma unroll
    for (int k4 = 0; k4 < 4; k4++) {
      union { short8 v; u16 u[8]; } Uh, Ul;
      long col0 = wave * 128 + k4 * 32 + kq * 8;
#pragma unroll
      for (int i = 0; i < 8; i++) splitf(w_hh[row + col0 + i], Uh.u[i], Ul.u[i]);
      wfh[q][k4] = Uh.v; wfl[q][k4] = Ul.v;
    }
  }
  float bu = b_uh_p[0];

  int jj = t & 15, bbt = t >> 4;        // wave0 cell mapping (contiguous h stores)
  float c_reg = 0.f, h_reg = 0.f;

  uint32_t* hgrp = hpk + (long)group * 4096;   // [par][4b][512] u32
  u64*      pgrp = prt + (long)group * 256;    // [par][4b][32]

  __syncthreads();

  for (int s = 0; s < TP; s++) {
    int par = s & 1, np = par ^ 1;
    // xq for CURRENT step (wave0 cells): 1KB contiguous per wg, issued before polls
    f32x4 xq;
    if (t < 64) {
      const float* xb = xpg + (((long)group * 512 + s) * 32 + slot) * 256;
      float x0 = xb[0 * 64 + jj * 4 + bbt];
      float x1 = xb[1 * 64 + jj * 4 + bbt];
      float x2 = xb[2 * 64 + jj * 4 + bbt];
      float x3 = xb[3 * 64 + jj * 4 + bbt];
      xq = (f32x4){x0, x1, x2, x3};
    }
    // ---- stage h+parts (all 256 threads; thread covers batch t>>6, units (t&63)*8..+8,
    //      which all come from ONE producer slot (t&63)>>1)
    int b = t >> 6, u0 = (t & 63) * 8;
    if (s == 0) {
      *(u32x4*)&sh_hi[b * 528 + u0] = (u32x4){0u, 0u, 0u, 0u};
      *(u32x4*)&sh_lo[b * 528 + u0] = (u32x4){0u, 0u, 0u, 0u};
    } else {
      int pslot = (t & 63) >> 1;
      const u64* pw = pgrp + (long)par * 128 + b * 32 + pslot;
      u64 w;
      do {
        w = __hip_atomic_load(pw, __ATOMIC_RELAXED, __HIP_MEMORY_SCOPE_AGENT);
      } while ((uint32_t)(w >> 32) != (uint32_t)s);
      if ((t & 1) == 0) sparts[b][pslot] = __uint_as_float((uint32_t)w);
      // certified: producer's h stores are LLC-visible; bulk-load retry-free
      const u64* hp = (const u64*)(hgrp + (long)par * 2048 + b * 512 + u0);
      u64 v0 = __hip_atomic_load(hp,     __ATOMIC_RELAXED, __HIP_MEMORY_SCOPE_AGENT);
      u64 v1 = __hip_atomic_load(hp + 1, __ATOMIC_RELAXED, __HIP_MEMORY_SCOPE_AGENT);
      u64 v2 = __hip_atomic_load(hp + 2, __ATOMIC_RELAXED, __HIP_MEMORY_SCOPE_AGENT);
      u64 v3 = __hip_atomic_load(hp + 3, __ATOMIC_RELAXED, __HIP_MEMORY_SCOPE_AGENT);
      uint32_t p[8] = {(uint32_t)v0, (uint32_t)(v0 >> 32), (uint32_t)v1, (uint32_t)(v1 >> 32),
                       (uint32_t)v2, (uint32_t)(v2 >> 32), (uint32_t)v3, (uint32_t)(v3 >> 32)};
      u32x4 hv, lv;
#pragma unroll
      for (int r = 0; r < 4; r++) {
        hv[r] = __builtin_amdgcn_perm(p[2 * r + 1], p[2 * r], 0x07060302u);
        lv[r] = __builtin_amdgcn_perm(p[2 * r + 1], p[2 * r], 0x05040100u);
      }
      *(u32x4*)&sh_hi[b * 528 + u0] = hv;
      *(u32x4*)&sh_lo[b * 528 + u0] = lv;
    }
    __syncthreads();   // staged data visible; also orders vs prev epilogue LDS reads
    // ---- u-update (t<4) from staged parts; identical fixed order in all 32 wgs
    if (s > 0 && t < 4) {
      float a = 0.f;
#pragma unroll
      for (int i = 0; i < 32; i++) a += sparts[t][i];
      float du = sigm(a + bu);
      float up = u_l[t], ubp = ubin_l[t];
      float un = (ubp > 0.5f) ? du : (up + fminf(du, 1.f - up));
      u_l[t] = un; ubin_l[t] = rintf(un);
    }
    // ---- MFMA: wave w does its K-quarter for all 4 gates (12 indep chains)
    f32x4 A0[4], A1[4], A2[4];
#pragma unroll
    for (int q = 0; q < 4; q++) {
      A0[q] = (f32x4){0.f, 0.f, 0.f, 0.f}; A1[q] = A0[q]; A2[q] = A0[q];
    }
#pragma unroll
    for (int k4 = 0; k4 < 4; k4++) {
      int ko = (wave * 4 + k4) * 32 + kq * 8;
      short8 bh = *(const short8*)&sh_hi[nbc * 528 + ko];
      short8 bl = *(const short8*)&sh_lo[nbc * 528 + ko];
#pragma unroll
      for (int q = 0; q < 4; q++) {
        A0[q] = __builtin_amdgcn_mfma_f32_16x16x32_bf16(wfh[q][k4], bh, A0[q], 0, 0, 0);
        A1[q] = __builtin_amdgcn_mfma_f32_16x16x32_bf16(wfh[q][k4], bl, A1[q], 0, 0, 0);
        A2[q] = __builtin_amdgcn_mfma_f32_16x16x32_bf16(wfl[q][k4], bh, A2[q], 0, 0, 0);
      }
    }
    if (um < 4) {
#pragma unroll
      for (int q = 0; q < 4; q++)
#pragma unroll
        for (int r = 0; r < 4; r++)
          gpart[wave][q][kq * 4 + r][um] = (A0[q][r] + A1[q][r]) + A2[q][r];
    }
    __syncthreads();
    // ---- epilogue: one LSTM cell per thread (wave 0 only); waves 1-3 loop ahead
    if (t < 64) {
      float g[4];
#pragma unroll
      for (int q = 0; q < 4; q++) {
        float a = xq[q];
#pragma unroll
        for (int w = 0; w < 4; w++) a += gpart[w][q][jj][bbt];
        g[q] = a;
      }
      float ig = sigm(g[0]), fg = sigm(g[1]), og = sigm(g[3]);
      float gt = tanh_fast(g[2]);
      float ct = fg * c_reg + ig * gt;
      float ht = og * tanh_fast(ct);
      bool upd = ubin_l[bbt] > 0.5f;
      float cn = upd ? ct : c_reg;
      float hn = upd ? ht : h_reg;
      c_reg = cn; h_reg = hn;
      u16 hhi, hlo; splitf(hn, hhi, hlo);
      uint32_t pk = ((uint32_t)hhi << 16) | (uint32_t)hlo;
      // untagged h store: lanes contiguous in jj -> 4 chunks of 64B
      __hip_atomic_store(hgrp + (long)np * 2048 + bbt * 512 + slot * 16 + jj, pk,
                         __ATOMIC_RELAXED, __HIP_MEMORY_SCOPE_AGENT);
      float pr = cn * wuh_l[jj];
      pr += __shfl_xor(pr, 1); pr += __shfl_xor(pr, 2);
      pr += __shfl_xor(pr, 4); pr += __shfl_xor(pr, 8);
      if (s == TLAST) outp[(long)(group * 4 + bbt) * 512 + slot * 16 + jj] = hn;
      // order: h stores ack'd at coherence point BEFORE the certifying parts store
      __threadfence_block();   // s_waitcnt vmcnt(0), no cache maintenance
      if ((t & 15) == 0) {
        u64 pw = ((u64)(uint32_t)(s + 1) << 32) | (u64)__float_as_uint(pr);
        __hip_atomic_store(pgrp + (long)np * 128 + bbt * 32 + slot, pw,
                           __ATOMIC_RELAXED, __HIP_MEMORY_SCOPE_AGENT);
      }
    }
    // no barrier: next staging (sh writes) is safe — all frag reads preceded the
    // gpart barrier; wave0's gpart reads precede its own next-iteration barrier#1.
  }
}

// ---------------- launcher ----------------
extern "C" void kernel_launch(void* const* d_in, const int* in_sizes, int n_in,
                              void* d_out, int out_size, void* d_ws, size_t ws_size,
                              hipStream_t stream) {
  const float* x      = (const float*)d_in[0];
  const float* conv_w = (const float*)d_in[1];
  const float* conv_b = (const float*)d_in[2];
  const float* gamma  = (const float*)d_in[3];
  const float* beta   = (const float*)d_in[4];
  const float* mean   = (const float*)d_in[5];
  const float* var    = (const float*)d_in[6];
  const float* w_ih   = (const float*)d_in[7];
  const float* w_hh   = (const float*)d_in[8];
  const float* b_ih   = (const float*)d_in[9];
  const float* b_hh   = (const float*)d_in[10];
  const float* w_uh   = (const float*)d_in[11];
  const float* b_uh   = (const float*)d_in[12];
  float* out = (float*)d_out;

  if (ws_size < WS_NEED) return;  // workspace too small: fail visibly via absmax

  char* w = (char*)d_ws;
  uint32_t* hpk = (uint32_t*)(w + HPK_OFF);
  u64*   prt   = (u64*)(w + PRT_OFF);
  float* xp    = (float*)(w + XP_OFF);
  u16*   xh    = (u16*)(w + XH_OFF);
  u16*   xl    = (u16*)(w + XL_OFF);
  u16*   xsh   = (u16*)(w + XSH_OFF);
  u16*   xsl   = (u16*)(w + XSL_OFF);
  u16*   wch   = (u16*)(w + WCH_OFF);
  u16*   wcl   = (u16*)(w + WCL_OFF);
  u16*   wihh  = (u16*)(w + WIHH_OFF);
  u16*   wihl  = (u16*)(w + WIHL_OFF);

  // no memset: parts tags self-validate (0xAA poison never matches 1..510);
  // h validity is certified by parts tags; h0/c0/u0 are zeros inside scan_kernel.

  prep_kernel<<<19072, 256, 0, stream>>>(x, conv_w, w_ih, xh, xl, wch, wcl, wihh, wihl);

  // conv GEMM: M=256(f) N=16384 K=640 -> xs (relu+BN, bf16 hi/lo, [n][f])
  gemm_kernel<0><<<2 * 128, 256, 0, stream>>>(wch, wcl, xh, xl,
                                              conv_b, gamma, beta, mean, var,
                                              xsh, xsl, nullptr);
  // proj GEMM: M=2048(g) N=16384 K=256 -> xp fp32 scan-coalesced (+ b_ih + b_hh)
  gemm_kernel<1><<<16 * 128, 256, 0, stream>>>(wihh, wihl, xsh, xsl,
                                               b_ih, b_hh, nullptr, nullptr, nullptr,
                                               nullptr, nullptr, xp);
  // persistent scan: 8 groups x 32 wgs (XCD-local heuristic), certify-via-parts
  scan_kernel<<<GWG, 256, 0, stream>>>(xp, w_hh, w_uh, b_uh, hpk, prt, out);
}